// Round 11
// baseline (549.332 us; speedup 1.0000x reference)
//
#include <hip/hip_runtime.h>
#include <math.h>

#define L_SEQ 2048
#define BS 8
#define EMB 512
#define NHEAD 8
#define DH 64
#define NB (BS*NHEAD)   // 64 batch-heads
#define SCALE_Q 0.18033688f   // 0.125 * log2(e): folded into Q so p = exp2(acc)
#define INV_2PI 0.15915494f

typedef short short8  __attribute__((ext_vector_type(8)));
typedef short short4v __attribute__((ext_vector_type(4)));
typedef float f32x4   __attribute__((ext_vector_type(4)));

// ---------------------------------------------------------------- f32 -> bf16 (RNE) helpers
__device__ __forceinline__ short f2bf(float x) {
    unsigned u = __float_as_uint(x);
    unsigned r = (u + 0x7FFFu + ((u >> 16) & 1u)) >> 16;
    return (short)r;
}
__device__ __forceinline__ float bf2f(short h) {
    return __uint_as_float(((unsigned)(unsigned short)h) << 16);
}

// ---------------------------------------------------------------- fused embed + posenc(inline trig+freq) + A-hi frags + embsum
// block = (b, 128-l chunk, 128-e chunk); thread: e4l = t&31, lsub = t>>5 (16 l's each).
// freq computed inline per thread (same double-pow chain as old freq_kernel);
// pe via v_sin/v_cos on fract(ph/2pi) (error ~1e-4 rad << bf16 floor).
__global__ __launch_bounds__(256) void embed_kernel(const int* __restrict__ inputs,
                                                    const float* __restrict__ table,
                                                    short* __restrict__ ahi,
                                                    float* __restrict__ embsum) {
    __shared__ float4 red[32][8];
    int b  = blockIdx.x;        // 0..7
    int lc = blockIdx.y;        // 0..15
    int ec = blockIdx.z;        // 0..3
    int t  = threadIdx.x;
    int e4l  = t & 31;          // float4 index within 128-float e-chunk
    int lsub = t >> 5;          // 0..7
    int e4 = ec*32 + e4l;
    int e0 = e4*4;
    int ks = e0 >> 5;
    int lanehi = ((e0 >> 3) & 3) << 4;
    int j0 = e0 & 7;
    double rdbl = pow(10000.0, -1.0 / 256.0);
    float rf = (float)rdbl;                      // match reference's f32 r
    float fa = (float)pow((double)rf, (double)(e4*2));
    float fb = (float)pow((double)rf, (double)(e4*2 + 1));
    float4 sum = {0.f, 0.f, 0.f, 0.f};
    #pragma unroll 4
    for (int i = 0; i < 16; i++) {
        int l = lc*128 + lsub*16 + i;
        int tok = inputs[b*L_SEQ + l];
        float4 tv = reinterpret_cast<const float4*>(table)[(size_t)tok*128 + e4];
        float lf = (float)l;
        float ra = lf * fa * INV_2PI;  ra -= floorf(ra);
        float rb = lf * fb * INV_2PI;  rb -= floorf(rb);
        float4 o;
        o.x = tv.x + __builtin_amdgcn_sinf(ra);
        o.y = tv.y + __builtin_amdgcn_cosf(ra);
        o.z = tv.z + __builtin_amdgcn_sinf(rb);
        o.w = tv.w + __builtin_amdgcn_cosf(rb);
        sum.x += o.x; sum.y += o.y; sum.z += o.z; sum.w += o.w;
        int m = l*BS + b;                       // A row
        int tile = m >> 4;
        int lane = (m & 15) + lanehi;
        size_t off = ((((size_t)tile*16 + ks) << 6) + lane)*8 + j0;
        short4v h4;
        h4[0] = f2bf(o.x); h4[1] = f2bf(o.y); h4[2] = f2bf(o.z); h4[3] = f2bf(o.w);
        *reinterpret_cast<short4v*>(ahi + off) = h4;
    }
    red[e4l][lsub] = sum;
    __syncthreads();
    if (t < 32) {
        float4 s = red[t][0];
        #pragma unroll
        for (int i = 1; i < 8; i++) {
            float4 v = red[t][i];
            s.x += v.x; s.y += v.y; s.z += v.z; s.w += v.w;
        }
        int e = ec*128 + t*4;
        atomicAdd(&embsum[b*EMB + e + 0], s.x);
        atomicAdd(&embsum[b*EMB + e + 1], s.y);
        atomicAdd(&embsum[b*EMB + e + 2], s.z);
        atomicAdd(&embsum[b*EMB + e + 3], s.w);
    }
}

// ---------------------------------------------------------------- W -> hi/lo frag split
__global__ __launch_bounds__(256) void wsplit_kernel(const float* __restrict__ src,
                                                     short8* __restrict__ hi,
                                                     short8* __restrict__ lo) {
    int idx = blockIdx.x*256 + threadIdx.x;    // over rows*64
    int c = idx & 63;                          // k-chunk of 8
    int r = idx >> 6;
    const float4* s4 = reinterpret_cast<const float4*>(src + (size_t)r*512 + c*8);
    float4 f0 = s4[0], f1 = s4[1];
    int ks   = c >> 2;
    int lane = (r & 15) + ((c & 3) << 4);
    int tile = r >> 4;
    float v[8] = {f0.x,f0.y,f0.z,f0.w,f1.x,f1.y,f1.z,f1.w};
    short8 h8, l8;
    #pragma unroll
    for (int q = 0; q < 8; q++) {
        short hb = f2bf(v[q]);
        h8[q] = hb;
        l8[q] = f2bf(v[q] - bf2f(hb));
    }
    size_t o = (((size_t)tile*16 + ks) << 6) + lane;
    hi[o] = h8; lo[o] = l8;
}

// ---------------------------------------------------------------- QKV GEMM: 2-term split-bf16 MFMA
// C = Ah*Bh + Ah*Bl  (Al*Bh dropped: ~2^-9 relative error, well under tolerance).
// A-hi + B hi/lo pre-frag'd in global; reg-staged, conflict-free LDS.
// XCD-bijective 1D grid: 1536 blocks = 8 xcd x (12 nb inner x 16 mbi).
// Epilogue writes q/k DIRECTLY in attention frag layout, v as bf16 rows.
// __launch_bounds__(256, 6): pin 6 blocks/CU (VGPR cap -> 84) — R10 showed module-context
// regalloc drift pushed this kernel to 88 VGPR and off the occupancy cliff (rule #19).
__global__ __launch_bounds__(256, 6) void qkv_mfma_kernel(const short8* __restrict__ ahi,
                                                          const short8* __restrict__ bhi,
                                                          const short8* __restrict__ blo,
                                                          const float* __restrict__ bias,
                                                          short* __restrict__ qbf_s,
                                                          short* __restrict__ kbf_s,
                                                          short* __restrict__ vg_s) {
    __shared__ short8 sA[8][64];      // [m-tile][lane] 8KB
    __shared__ short8 sB[2][8][64];   // [hi/lo][n-tile][lane] 16KB
    int id  = blockIdx.x;
    int xcd = id & 7, pos = id >> 3;  // 192 per XCD
    int nb  = pos % 12;               // nb inner -> A-tile's 12 consumers co-resident
    int mb  = xcd*16 + pos/12;        // 0..127
    int t  = threadIdx.x;
    int w  = t >> 6, lane = t & 63;
    int wr = w >> 1, wc = w & 1;

    f32x4 acc[4][4];
    #pragma unroll
    for (int i = 0; i < 4; i++)
        #pragma unroll
        for (int j = 0; j < 4; j++)
            acc[i][j] = (f32x4){0.f, 0.f, 0.f, 0.f};

    // 24 frag-lines: li<8 -> A-hi tile li; li>=8 -> B (idx=li-8: h=idx&1, ti=idx>>1).
    // wave w stages lines w*6..w*6+5.
    short8 stg[6];
    #pragma unroll
    for (int i = 0; i < 6; i++) {
        int li = w*6 + i;
        const short8* p;
        if (li < 8) p = &ahi[((((size_t)(mb*8 + li))*16 + 0) << 6) + lane];
        else {
            int idx = li - 8;
            const short8* base = (idx & 1) ? blo : bhi;
            p = &base[((((size_t)(nb*8 + (idx >> 1)))*16 + 0) << 6) + lane];
        }
        stg[i] = *p;
    }
    for (int ks = 0; ks < 16; ks++) {
        __syncthreads();   // prev compute done
        #pragma unroll
        for (int i = 0; i < 6; i++) {
            int li = w*6 + i;
            if (li < 8) sA[li][lane] = stg[i];
            else { int idx = li - 8; sB[idx & 1][idx >> 1][lane] = stg[i]; }
        }
        __syncthreads();
        if (ks < 15) {
            #pragma unroll
            for (int i = 0; i < 6; i++) {
                int li = w*6 + i;
                const short8* p;
                if (li < 8) p = &ahi[((((size_t)(mb*8 + li))*16 + (ks+1)) << 6) + lane];
                else {
                    int idx = li - 8;
                    const short8* base = (idx & 1) ? blo : bhi;
                    p = &base[((((size_t)(nb*8 + (idx >> 1)))*16 + (ks+1)) << 6) + lane];
                }
                stg[i] = *p;
            }
        }
        short8 Ah[4];
        #pragma unroll
        for (int fi = 0; fi < 4; fi++)
            Ah[fi] = sA[wr*4 + fi][lane];
        #pragma unroll
        for (int fj = 0; fj < 4; fj++) {
            short8 Bh = sB[0][wc*4 + fj][lane];
            short8 Bl = sB[1][wc*4 + fj][lane];
            #pragma unroll
            for (int fi = 0; fi < 4; fi++) {
                acc[fi][fj] = __builtin_amdgcn_mfma_f32_16x16x32_bf16(Ah[fi], Bh, acc[fi][fj], 0, 0, 0);
                acc[fi][fj] = __builtin_amdgcn_mfma_f32_16x16x32_bf16(Ah[fi], Bl, acc[fi][fj], 0, 0, 0);
            }
        }
    }
    // epilogue: bias + scatter; q (pre-scaled) / k straight into frag layout, v as bf16 rows
    int row0 = (lane >> 4) * 4;
    int col  = lane & 15;
    #pragma unroll
    for (int fj = 0; fj < 4; fj++) {
        int n   = nb*128 + wc*64 + fj*16 + col;
        int h   = n / 192;
        int sel = (n % 192) / 64;
        float bn = bias[n];
        int nn = n & 63;
        #pragma unroll
        for (int fi = 0; fi < 4; fi++) {
            int m0 = mb*128 + wr*64 + fi*16 + row0;
            #pragma unroll
            for (int r = 0; r < 4; r++) {
                int m = m0 + r;
                int l = m >> 3, b = m & 7;
                float val = acc[fi][fj][r] + bn;
                if (sel == 2) {
                    vg_s[(((size_t)(b*NHEAD + h))*L_SEQ + l)*DH + nn] = f2bf(val);
                } else {
                    int bh   = b*NHEAD + h;
                    int tile = l >> 4;
                    int kss  = nn >> 5;
                    int ln2  = (l & 15) + (((nn >> 3) & 3) << 4);
                    size_t off = ((((size_t)(bh*128 + tile)*2 + kss) << 6) + ln2)*8 + (nn & 7);
                    if (sel == 1) kbf_s[off] = f2bf(val);
                    else          qbf_s[off] = f2bf(val * SCALE_Q);
                }
            }
        }
    }
}

// ---------------------------------------------------------------- pass 1: l[q] += partial sum_k exp2(s)
// Q pre-scaled by 0.125*log2e -> p = exp2(acc). k-range quarter-split by blockIdx.z
// (additive partials, atomicAdd merge -> cq zeroed by memset).
// Hoisted zero-C constant + 16 independent accumulators (break add chains).
__global__ __launch_bounds__(256) void ml_mfma_kernel(const short8* __restrict__ qbf,
                                                      const short8* __restrict__ kbf,
                                                      float* __restrict__ cq) {
    int bh = blockIdx.x, wv = threadIdx.x >> 6, lane = threadIdx.x & 63;
    int z  = blockIdx.z;                         // k-quarter (32 tiles)
    int qt0 = (blockIdx.y*4 + wv)*4;             // 4 q-tiles of 16
    short8 bq0[4], bq1[4];
    #pragma unroll
    for (int j = 0; j < 4; j++) {
        const short8* qp = qbf + (((size_t)(bh*128 + qt0 + j)*2) << 6) + lane;
        bq0[j] = qp[0]; bq1[j] = qp[64];
    }
    const short8* kp = kbf + ((size_t)bh << 14) + lane + (size_t)z*4096;
    const f32x4 z4 = {0.f, 0.f, 0.f, 0.f};
    float lsum[4][4] = {};
    for (int t = 0; t < 32; t++) {
        short8 a0 = kp[0], a1 = kp[64];
        kp += 128;
        #pragma unroll
        for (int j = 0; j < 4; j++) {
            f32x4 acc = __builtin_amdgcn_mfma_f32_16x16x32_bf16(a0, bq0[j], z4, 0, 0, 0);
            acc = __builtin_amdgcn_mfma_f32_16x16x32_bf16(a1, bq1[j], acc, 0, 0, 0);
            #pragma unroll
            for (int r = 0; r < 4; r++)
                lsum[j][r] += (acc[r] != 0.f) ? __builtin_amdgcn_exp2f(acc[r]) : 0.f;  // mask: s==0
        }
    }
    #pragma unroll
    for (int j = 0; j < 4; j++) {
        float s = (lsum[j][0] + lsum[j][1]) + (lsum[j][2] + lsum[j][3]);
        s += __shfl_xor(s, 16);
        s += __shfl_xor(s, 32);
        lsum[j][0] = s;
    }
    if (lane < 16) {
        #pragma unroll
        for (int j = 0; j < 4; j++)
            atomicAdd(&cq[(size_t)bh*L_SEQ + (qt0+j)*16 + lane], lsum[j][0]);
    }
}

// ---------------------------------------------------------------- invert l sums: cq <- 1/cq (0 if l<=0)
__global__ __launch_bounds__(256) void inv_kernel(float* __restrict__ cq) {
    int i = blockIdx.x*256 + threadIdx.x;       // over NB*L/4 = 32768
    float4 v = reinterpret_cast<float4*>(cq)[i];
    float4 o;
    o.x = (v.x > 0.f) ? __builtin_amdgcn_rcpf(v.x) : 0.f;
    o.y = (v.y > 0.f) ? __builtin_amdgcn_rcpf(v.y) : 0.f;
    o.z = (v.z > 0.f) ? __builtin_amdgcn_rcpf(v.z) : 0.f;
    o.w = (v.w > 0.f) ? __builtin_amdgcn_rcpf(v.w) : 0.f;
    reinterpret_cast<float4*>(cq)[i] = o;
}

// ---------------------------------------------------------------- pass 2: w_k += partial sum_q exp2(s)*invl[q]
// q-range quarter-split by blockIdx.z (additive partials -> wk zeroed). cq pre-inverted.
__global__ __launch_bounds__(256) void kw_mfma_kernel(const short8* __restrict__ qbf,
                                                      const short8* __restrict__ kbf,
                                                      const float* __restrict__ cq,
                                                      float* __restrict__ wk) {
    int bh = blockIdx.x, wv = threadIdx.x >> 6, lane = threadIdx.x & 63;
    int z  = blockIdx.z;                         // q-quarter
    int kt0 = (blockIdx.y*4 + wv)*4;             // 4 k-tiles of 16
    short8 bk0[4], bk1[4];
    #pragma unroll
    for (int j = 0; j < 4; j++) {
        const short8* kp = kbf + (((size_t)(bh*128 + kt0 + j)*2) << 6) + lane;
        bk0[j] = kp[0]; bk1[j] = kp[64];
    }
    const short8* qp = qbf + ((size_t)bh << 14) + lane + (size_t)z*4096;
    const float4* cp = reinterpret_cast<const float4*>(cq + (size_t)bh*L_SEQ) + (lane >> 4) + z*128;
    const f32x4 z4 = {0.f, 0.f, 0.f, 0.f};
    float w[4][4] = {};
    for (int t = 0; t < 32; t++) {
        short8 a0 = qp[0], a1 = qp[64];
        qp += 128;
        float4 c4 = cp[0]; cp += 4;              // invl for rows q = z*512 + t*16 + (lane>>4)*4 + r
        float cr[4] = {c4.x, c4.y, c4.z, c4.w};
        #pragma unroll
        for (int j = 0; j < 4; j++) {
            f32x4 acc = __builtin_amdgcn_mfma_f32_16x16x32_bf16(a0, bk0[j], z4, 0, 0, 0);
            acc = __builtin_amdgcn_mfma_f32_16x16x32_bf16(a1, bk1[j], acc, 0, 0, 0);
            #pragma unroll
            for (int r = 0; r < 4; r++) {
                float p = __builtin_amdgcn_exp2f(acc[r]);
                w[j][r] += (acc[r] != 0.f) ? p*cr[r] : 0.f;
            }
        }
    }
    #pragma unroll
    for (int j = 0; j < 4; j++) {
        float s = (w[j][0] + w[j][1]) + (w[j][2] + w[j][3]);
        s += __shfl_xor(s, 16);
        s += __shfl_xor(s, 32);
        w[j][0] = s;
    }
    if (lane < 16) {
        #pragma unroll
        for (int j = 0; j < 4; j++)
            atomicAdd(&wk[(size_t)bh*L_SEQ + (kt0+j)*16 + lane], w[j][0]);
    }
}

// ---------------------------------------------------------------- pass 3: O = sum_k w_k * V_k (bf16 V)
__global__ __launch_bounds__(256) void pv_kernel(const short* __restrict__ vg_s,
                                                 const float* __restrict__ wk,
                                                 float* __restrict__ O) {
    __shared__ float red[256];
    int bidx = blockIdx.x;                       // 0..63
    int seg  = blockIdx.y;                       // 0..7 (256 keys each)
    int t    = threadIdx.x;
    int d    = t & 63;
    int ks   = t >> 6;                           // 0..3
    const short* vrow = vg_s + ((size_t)bidx*L_SEQ + seg*256)*DH;
    const float* wrow = wk + (size_t)bidx*L_SEQ + seg*256;
    float acc = 0.f;
    for (int k = ks; k < 256; k += 4)
        acc += wrow[k] * bf2f(vrow[k*64 + d]);
    red[t] = acc;
    __syncthreads();
    if (t < 128) red[t] += red[t + 128];
    __syncthreads();
    if (t < 64) atomicAdd(&O[bidx*64 + t], red[t] + red[t + 64]);
}

// ---------------------------------------------------------------- GN + residual + LN -> x, xn
__global__ __launch_bounds__(256) void ln_kernel(const float* __restrict__ O,
                                                 const float* __restrict__ embsum,
                                                 const int* __restrict__ lens,
                                                 const float* __restrict__ gn_w,
                                                 const float* __restrict__ gn_b,
                                                 const float* __restrict__ ln_w,
                                                 const float* __restrict__ ln_b,
                                                 float* __restrict__ xbuf,
                                                 float* __restrict__ xnbuf) {
    int b = blockIdx.x;
    int t = threadIdx.x;
    __shared__ float x[EMB];
    __shared__ float rbuf[16];
    {
        int h = t >> 5;            // 0..7
        int i32 = t & 31;
        float v0 = O[b*EMB + h*64 + i32];
        float v1 = O[b*EMB + h*64 + i32 + 32];
        float s = v0+v1, ss = v0*v0 + v1*v1;
        #pragma unroll
        for (int off = 16; off >= 1; off >>= 1) {
            s  += __shfl_xor(s,  off, 32);
            ss += __shfl_xor(ss, off, 32);
        }
        float mu  = s * (1.f/64.f);
        float var = ss * (1.f/64.f) - mu*mu;
        float rstd = rsqrtf(var + 1e-5f);
        float gw = gn_w[h], gb = gn_b[h];
        float len = (float)lens[b];
        x[h*64+i32]    = (v0-mu)*rstd*gw + gb + embsum[b*EMB + h*64+i32] / len;
        x[h*64+i32+32] = (v1-mu)*rstd*gw + gb + embsum[b*EMB + h*64+i32+32] / len;
    }
    __syncthreads();
    float xv0 = x[t], xv1 = x[t+256];
    {
        float s = xv0+xv1, ss = xv0*xv0 + xv1*xv1;
        #pragma unroll
        for (int off = 32; off >= 1; off >>= 1) {
            s  += __shfl_xor(s,  off);
            ss += __shfl_xor(ss, off);
        }
        int wid = t >> 6;
        if ((t & 63) == 0) { rbuf[wid] = s; rbuf[8+wid] = ss; }
        __syncthreads();
        float S  = rbuf[0]+rbuf[1]+rbuf[2]+rbuf[3];
        float SS = rbuf[8]+rbuf[9]+rbuf[10]+rbuf[11];
        float mu  = S * (1.f/512.f);
        float var = SS * (1.f/512.f) - mu*mu;
        float rstd = rsqrtf(var + 1e-5f);
        xnbuf[b*EMB + t]       = (xv0-mu)*rstd*ln_w[t]     + ln_b[t];
        xnbuf[b*EMB + t + 256] = (xv1-mu)*rstd*ln_w[t+256] + ln_b[t+256];
        xbuf[b*EMB + t]        = xv0;
        xbuf[b*EMB + t + 256]  = xv1;
    }
}

// ---------------------------------------------------------------- MLP layer 1: h1 = tanh(xn @ w1^T + b1)
__global__ __launch_bounds__(256) void mlp1_kernel(const float* __restrict__ xnbuf,
                                                   const float* __restrict__ w1,
                                                   const float* __restrict__ b1,
                                                   float* __restrict__ h1buf) {
    __shared__ float sxn[BS][EMB];     // 16KB
    int t = threadIdx.x;
    #pragma unroll
    for (int i = 0; i < 4; i++)
        reinterpret_cast<float4*>(&sxn[0][0])[t + 256*i] =
            reinterpret_cast<const float4*>(xnbuf)[t + 256*i];
    __syncthreads();
    int b = t & 7;
    int j = blockIdx.x*32 + (t >> 3);  // 0..1023
    const float4* wr = reinterpret_cast<const float4*>(w1 + (size_t)j*512);
    const float4* xr = reinterpret_cast<const float4*>(&sxn[b][0]);
    float a0 = 0.f, a1 = 0.f;
    #pragma unroll 8
    for (int i = 0; i < 128; i += 2) {
        float4 wv = wr[i],   xv = xr[i];
        a0 += wv.x*xv.x + wv.y*xv.y + wv.z*xv.z + wv.w*xv.w;
        float4 wv1 = wr[i+1], xv1 = xr[i+1];
        a1 += wv1.x*xv1.x + wv1.y*xv1.y + wv1.z*xv1.z + wv1.w*xv1.w;
    }
    h1buf[b*1024 + j] = tanhf(a0 + a1 + b1[j]);
}

// ---------------------------------------------------------------- MLP layer 2: out = x + h1 @ w2^T + b2
__global__ __launch_bounds__(256) void mlp2_kernel(const float* __restrict__ h1buf,
                                                   const float* __restrict__ xbuf,
                                                   const float* __restrict__ w2,
                                                   const float* __restrict__ b2,
                                                   float* __restrict__ out) {
    __shared__ float sh1[BS][2*EMB];   // 32KB
    int t = threadIdx.x;
    #pragma unroll
    for (int i = 0; i < 8; i++)
        reinterpret_cast<float4*>(&sh1[0][0])[t + 256*i] =
            reinterpret_cast<const float4*>(h1buf)[t + 256*i];
    __syncthreads();
    int b = t & 7;
    int e = blockIdx.x*32 + (t >> 3);  // 0..511
    const float4* wr = reinterpret_cast<const float4*>(w2 + (size_t)e*1024);
    const float4* hr = reinterpret_cast<const float4*>(&sh1[b][0]);
    float a0 = 0.f, a1 = 0.f;
    #pragma unroll 8
    for (int i = 0; i < 256; i += 2) {
        float4 wv = wr[i],   hv = hr[i];
        a0 += wv.x*hv.x + wv.y*hv.y + wv.z*hv.z + wv.w*hv.w;
        float4 wv1 = wr[i+1], hv1 = hr[i+1];
        a1 += wv1.x*hv1.x + wv1.y*hv1.y + wv1.z*hv1.z + wv1.w*hv1.w;
    }
    out[b*EMB + e] = xbuf[b*EMB + e] + a0 + a1 + b2[e];
}

// ---------------------------------------------------------------- launch
extern "C" void kernel_launch(void* const* d_in, const int* in_sizes, int n_in,
                              void* d_out, int out_size, void* d_ws, size_t ws_size,
                              hipStream_t stream) {
    const int*   inputs    = (const int*)d_in[0];
    const int*   lens      = (const int*)d_in[1];
    const float* emb_table = (const float*)d_in[2];
    const float* qkv_w     = (const float*)d_in[3];
    const float* qkv_b     = (const float*)d_in[4];
    const float* gn_w      = (const float*)d_in[5];
    const float* gn_b      = (const float*)d_in[6];
    const float* ln_w      = (const float*)d_in[7];
    const float* ln_b      = (const float*)d_in[8];
    const float* w1        = (const float*)d_in[9];
    const float* b1        = (const float*)d_in[10];
    const float* w2        = (const float*)d_in[11];
    const float* b2        = (const float*)d_in[12];
    float* out = (float*)d_out;

    // ---- workspace map (floats). OFFSETS IDENTICAL TO R7..R10 (proven).
    // emb-f32, pe, alo, qkrows, freq regions unused/reserved for layout stability.
    float* ws = (float*)d_ws;
    const size_t NE = (size_t)L_SEQ*BS*EMB;       // 8,388,608
    float* emb    = ws;                           // region reused by kbf/qbf only
    float* vg     = emb + NE;                     // now bf16 rows (half the region used)
    float* pe_res = vg  + NE;                     // reserved
    float* afrag  = pe_res + (size_t)L_SEQ*EMB;
    short* ahi_s  = reinterpret_cast<short*>(afrag);
    float* qkrows = afrag + NE;                   // unused; reserved
    float* wfrag  = qkrows + NE;
    short8* bhi   = reinterpret_cast<short8*>(wfrag);
    short8* blo   = bhi + 98304;
    float* cqbuf  = wfrag + 786432;               // past BOTH bhi and blo
    float* wkbuf  = cqbuf + (size_t)NB*L_SEQ;     // 131072
    float* freq   = wkbuf + (size_t)NB*L_SEQ;     // 256 (reserved; freq now inline)
    float* embsum = freq + 256;                   // 4096
    float* Oacc   = embsum + BS*EMB;              // 4096
    float* xbuf   = Oacc + NB*DH;                 // 4096
    float* xnbuf  = xbuf + BS*EMB;                // 4096
    float* h1buf  = xnbuf + BS*EMB;               // 8192
    // q/k frag buffers alias emb region (written by qkv epilogue)
    short8* kbf = reinterpret_cast<short8*>(emb);             // 16 MB
    short8* qbf = kbf + (size_t)NB*128*2*64;                  // 16 MB

    // one memset covers cq + wk + freq(reserved) + embsum + Oacc (contiguous)
    hipMemsetAsync(cqbuf, 0, (2*(size_t)NB*L_SEQ + 256 + 2*BS*EMB) * sizeof(float), stream);

    embed_kernel<<<dim3(BS, 16, 4), 256, 0, stream>>>(inputs, emb_table, ahi_s, embsum);
    wsplit_kernel<<<384, 256, 0, stream>>>(qkv_w, bhi, blo);
    qkv_mfma_kernel<<<1536, 256, 0, stream>>>(reinterpret_cast<const short8*>(ahi_s),
                                              bhi, blo, qkv_b,
                                              reinterpret_cast<short*>(qbf),
                                              reinterpret_cast<short*>(kbf),
                                              reinterpret_cast<short*>(vg));
    ml_mfma_kernel<<<dim3(NB, 8, 4), 256, 0, stream>>>(qbf, kbf, cqbuf);
    inv_kernel<<<128, 256, 0, stream>>>(cqbuf);
    kw_mfma_kernel<<<dim3(NB, 8, 4), 256, 0, stream>>>(qbf, kbf, cqbuf, wkbuf);
    pv_kernel<<<dim3(NB, 8), 256, 0, stream>>>(reinterpret_cast<const short*>(vg), wkbuf, Oacc);
    ln_kernel<<<BS, 256, 0, stream>>>(Oacc, embsum, lens, gn_w, gn_b, ln_w, ln_b, xbuf, xnbuf);
    mlp1_kernel<<<32, 256, 0, stream>>>(xnbuf, w1, b1, h1buf);
    mlp2_kernel<<<16, 256, 0, stream>>>(h1buf, xbuf, w2, b2, out);
}

// Round 12
// 374.851 us; speedup vs baseline: 1.4655x; 1.4655x over previous
//
#include <hip/hip_runtime.h>
#include <math.h>

#define L_SEQ 2048
#define BS 8
#define EMB 512
#define NHEAD 8
#define DH 64
#define NB (BS*NHEAD)   // 64 batch-heads
#define SCALE_Q 0.18033688f   // 0.125 * log2(e): folded into Q so p = exp2(acc)
#define INV_2PI 0.15915494f

typedef short short8  __attribute__((ext_vector_type(8)));
typedef short short4v __attribute__((ext_vector_type(4)));
typedef float f32x4   __attribute__((ext_vector_type(4)));

// ---------------------------------------------------------------- f32 -> bf16 (RNE) helpers
__device__ __forceinline__ short f2bf(float x) {
    unsigned u = __float_as_uint(x);
    unsigned r = (u + 0x7FFFu + ((u >> 16) & 1u)) >> 16;
    return (short)r;
}
__device__ __forceinline__ float bf2f(short h) {
    return __uint_as_float(((unsigned)(unsigned short)h) << 16);
}

// ---------------------------------------------------------------- fused embed + posenc(inline trig+freq) + A-hi frags + embsum
__global__ __launch_bounds__(256) void embed_kernel(const int* __restrict__ inputs,
                                                    const float* __restrict__ table,
                                                    short* __restrict__ ahi,
                                                    float* __restrict__ embsum) {
    __shared__ float4 red[32][8];
    int b  = blockIdx.x;        // 0..7
    int lc = blockIdx.y;        // 0..15
    int ec = blockIdx.z;        // 0..3
    int t  = threadIdx.x;
    int e4l  = t & 31;          // float4 index within 128-float e-chunk
    int lsub = t >> 5;          // 0..7
    int e4 = ec*32 + e4l;
    int e0 = e4*4;
    int ks = e0 >> 5;
    int lanehi = ((e0 >> 3) & 3) << 4;
    int j0 = e0 & 7;
    double rdbl = pow(10000.0, -1.0 / 256.0);
    float rf = (float)rdbl;                      // match reference's f32 r
    float fa = (float)pow((double)rf, (double)(e4*2));
    float fb = (float)pow((double)rf, (double)(e4*2 + 1));
    float4 sum = {0.f, 0.f, 0.f, 0.f};
    #pragma unroll 4
    for (int i = 0; i < 16; i++) {
        int l = lc*128 + lsub*16 + i;
        int tok = inputs[b*L_SEQ + l];
        float4 tv = reinterpret_cast<const float4*>(table)[(size_t)tok*128 + e4];
        float lf = (float)l;
        float ra = lf * fa * INV_2PI;  ra -= floorf(ra);
        float rb = lf * fb * INV_2PI;  rb -= floorf(rb);
        float4 o;
        o.x = tv.x + __builtin_amdgcn_sinf(ra);
        o.y = tv.y + __builtin_amdgcn_cosf(ra);
        o.z = tv.z + __builtin_amdgcn_sinf(rb);
        o.w = tv.w + __builtin_amdgcn_cosf(rb);
        sum.x += o.x; sum.y += o.y; sum.z += o.z; sum.w += o.w;
        int m = l*BS + b;                       // A row
        int tile = m >> 4;
        int lane = (m & 15) + lanehi;
        size_t off = ((((size_t)tile*16 + ks) << 6) + lane)*8 + j0;
        short4v h4;
        h4[0] = f2bf(o.x); h4[1] = f2bf(o.y); h4[2] = f2bf(o.z); h4[3] = f2bf(o.w);
        *reinterpret_cast<short4v*>(ahi + off) = h4;
    }
    red[e4l][lsub] = sum;
    __syncthreads();
    if (t < 32) {
        float4 s = red[t][0];
        #pragma unroll
        for (int i = 1; i < 8; i++) {
            float4 v = red[t][i];
            s.x += v.x; s.y += v.y; s.z += v.z; s.w += v.w;
        }
        int e = ec*128 + t*4;
        atomicAdd(&embsum[b*EMB + e + 0], s.x);
        atomicAdd(&embsum[b*EMB + e + 1], s.y);
        atomicAdd(&embsum[b*EMB + e + 2], s.z);
        atomicAdd(&embsum[b*EMB + e + 3], s.w);
    }
}

// ---------------------------------------------------------------- W -> hi/lo frag split
__global__ __launch_bounds__(256) void wsplit_kernel(const float* __restrict__ src,
                                                     short8* __restrict__ hi,
                                                     short8* __restrict__ lo) {
    int idx = blockIdx.x*256 + threadIdx.x;    // over rows*64
    int c = idx & 63;                          // k-chunk of 8
    int r = idx >> 6;
    const float4* s4 = reinterpret_cast<const float4*>(src + (size_t)r*512 + c*8);
    float4 f0 = s4[0], f1 = s4[1];
    int ks   = c >> 2;
    int lane = (r & 15) + ((c & 3) << 4);
    int tile = r >> 4;
    float v[8] = {f0.x,f0.y,f0.z,f0.w,f1.x,f1.y,f1.z,f1.w};
    short8 h8, l8;
    #pragma unroll
    for (int q = 0; q < 8; q++) {
        short hb = f2bf(v[q]);
        h8[q] = hb;
        l8[q] = f2bf(v[q] - bf2f(hb));
    }
    size_t o = (((size_t)tile*16 + ks) << 6) + lane;
    hi[o] = h8; lo[o] = l8;
}

// ---------------------------------------------------------------- QKV GEMM: 2-term split-bf16 MFMA
// C = Ah*Bh + Ah*Bl  (Al*Bh dropped: ~2^-9 relative error, well under tolerance).
// PLAIN __launch_bounds__(256): R11's (256,6) pin forced the allocator under the
// accumulator live-set -> acc[4][4] spilled to scratch (VGPR 40, 1.07 GB HBM, 246us).
// Natural allocation (84-88 VGPR) is the optimum; do NOT cap below it.
__global__ __launch_bounds__(256) void qkv_mfma_kernel(const short8* __restrict__ ahi,
                                                       const short8* __restrict__ bhi,
                                                       const short8* __restrict__ blo,
                                                       const float* __restrict__ bias,
                                                       short* __restrict__ qbf_s,
                                                       short* __restrict__ kbf_s,
                                                       short* __restrict__ vg_s) {
    __shared__ short8 sA[8][64];      // [m-tile][lane] 8KB
    __shared__ short8 sB[2][8][64];   // [hi/lo][n-tile][lane] 16KB
    int id  = blockIdx.x;
    int xcd = id & 7, pos = id >> 3;  // 192 per XCD
    int nb  = pos % 12;               // nb inner -> A-tile's 12 consumers co-resident
    int mb  = xcd*16 + pos/12;        // 0..127
    int t  = threadIdx.x;
    int w  = t >> 6, lane = t & 63;
    int wr = w >> 1, wc = w & 1;

    f32x4 acc[4][4];
    #pragma unroll
    for (int i = 0; i < 4; i++)
        #pragma unroll
        for (int j = 0; j < 4; j++)
            acc[i][j] = (f32x4){0.f, 0.f, 0.f, 0.f};

    // 24 frag-lines: li<8 -> A-hi tile li; li>=8 -> B (idx=li-8: h=idx&1, ti=idx>>1).
    // wave w stages lines w*6..w*6+5.
    short8 stg[6];
    #pragma unroll
    for (int i = 0; i < 6; i++) {
        int li = w*6 + i;
        const short8* p;
        if (li < 8) p = &ahi[((((size_t)(mb*8 + li))*16 + 0) << 6) + lane];
        else {
            int idx = li - 8;
            const short8* base = (idx & 1) ? blo : bhi;
            p = &base[((((size_t)(nb*8 + (idx >> 1)))*16 + 0) << 6) + lane];
        }
        stg[i] = *p;
    }
    for (int ks = 0; ks < 16; ks++) {
        __syncthreads();   // prev compute done
        #pragma unroll
        for (int i = 0; i < 6; i++) {
            int li = w*6 + i;
            if (li < 8) sA[li][lane] = stg[i];
            else { int idx = li - 8; sB[idx & 1][idx >> 1][lane] = stg[i]; }
        }
        __syncthreads();
        if (ks < 15) {
            #pragma unroll
            for (int i = 0; i < 6; i++) {
                int li = w*6 + i;
                const short8* p;
                if (li < 8) p = &ahi[((((size_t)(mb*8 + li))*16 + (ks+1)) << 6) + lane];
                else {
                    int idx = li - 8;
                    const short8* base = (idx & 1) ? blo : bhi;
                    p = &base[((((size_t)(nb*8 + (idx >> 1)))*16 + (ks+1)) << 6) + lane];
                }
                stg[i] = *p;
            }
        }
        short8 Ah[4];
        #pragma unroll
        for (int fi = 0; fi < 4; fi++)
            Ah[fi] = sA[wr*4 + fi][lane];
        #pragma unroll
        for (int fj = 0; fj < 4; fj++) {
            short8 Bh = sB[0][wc*4 + fj][lane];
            short8 Bl = sB[1][wc*4 + fj][lane];
            #pragma unroll
            for (int fi = 0; fi < 4; fi++) {
                acc[fi][fj] = __builtin_amdgcn_mfma_f32_16x16x32_bf16(Ah[fi], Bh, acc[fi][fj], 0, 0, 0);
                acc[fi][fj] = __builtin_amdgcn_mfma_f32_16x16x32_bf16(Ah[fi], Bl, acc[fi][fj], 0, 0, 0);
            }
        }
    }
    // epilogue: bias + scatter; q (pre-scaled) / k straight into frag layout, v as bf16 rows
    int row0 = (lane >> 4) * 4;
    int col  = lane & 15;
    #pragma unroll
    for (int fj = 0; fj < 4; fj++) {
        int n   = nb*128 + wc*64 + fj*16 + col;
        int h   = n / 192;
        int sel = (n % 192) / 64;
        float bn = bias[n];
        int nn = n & 63;
        #pragma unroll
        for (int fi = 0; fi < 4; fi++) {
            int m0 = mb*128 + wr*64 + fi*16 + row0;
            #pragma unroll
            for (int r = 0; r < 4; r++) {
                int m = m0 + r;
                int l = m >> 3, b = m & 7;
                float val = acc[fi][fj][r] + bn;
                if (sel == 2) {
                    vg_s[(((size_t)(b*NHEAD + h))*L_SEQ + l)*DH + nn] = f2bf(val);
                } else {
                    int bh   = b*NHEAD + h;
                    int tile = l >> 4;
                    int kss  = nn >> 5;
                    int ln2  = (l & 15) + (((nn >> 3) & 3) << 4);
                    size_t off = ((((size_t)(bh*128 + tile)*2 + kss) << 6) + ln2)*8 + (nn & 7);
                    if (sel == 1) kbf_s[off] = f2bf(val);
                    else          qbf_s[off] = f2bf(val * SCALE_Q);
                }
            }
        }
    }
}

// ---------------------------------------------------------------- pass 1: l[q] += partial sum_k exp2(s)
__global__ __launch_bounds__(256) void ml_mfma_kernel(const short8* __restrict__ qbf,
                                                      const short8* __restrict__ kbf,
                                                      float* __restrict__ cq) {
    int bh = blockIdx.x, wv = threadIdx.x >> 6, lane = threadIdx.x & 63;
    int z  = blockIdx.z;                         // k-quarter (32 tiles)
    int qt0 = (blockIdx.y*4 + wv)*4;             // 4 q-tiles of 16
    short8 bq0[4], bq1[4];
    #pragma unroll
    for (int j = 0; j < 4; j++) {
        const short8* qp = qbf + (((size_t)(bh*128 + qt0 + j)*2) << 6) + lane;
        bq0[j] = qp[0]; bq1[j] = qp[64];
    }
    const short8* kp = kbf + ((size_t)bh << 14) + lane + (size_t)z*4096;
    const f32x4 z4 = {0.f, 0.f, 0.f, 0.f};
    float lsum[4][4] = {};
    for (int t = 0; t < 32; t++) {
        short8 a0 = kp[0], a1 = kp[64];
        kp += 128;
        #pragma unroll
        for (int j = 0; j < 4; j++) {
            f32x4 acc = __builtin_amdgcn_mfma_f32_16x16x32_bf16(a0, bq0[j], z4, 0, 0, 0);
            acc = __builtin_amdgcn_mfma_f32_16x16x32_bf16(a1, bq1[j], acc, 0, 0, 0);
            #pragma unroll
            for (int r = 0; r < 4; r++)
                lsum[j][r] += (acc[r] != 0.f) ? __builtin_amdgcn_exp2f(acc[r]) : 0.f;  // mask: s==0
        }
    }
    #pragma unroll
    for (int j = 0; j < 4; j++) {
        float s = (lsum[j][0] + lsum[j][1]) + (lsum[j][2] + lsum[j][3]);
        s += __shfl_xor(s, 16);
        s += __shfl_xor(s, 32);
        lsum[j][0] = s;
    }
    if (lane < 16) {
        #pragma unroll
        for (int j = 0; j < 4; j++)
            atomicAdd(&cq[(size_t)bh*L_SEQ + (qt0+j)*16 + lane], lsum[j][0]);
    }
}

// ---------------------------------------------------------------- invert l sums: cq <- 1/cq (0 if l<=0)
__global__ __launch_bounds__(256) void inv_kernel(float* __restrict__ cq) {
    int i = blockIdx.x*256 + threadIdx.x;       // over NB*L/4 = 32768
    float4 v = reinterpret_cast<float4*>(cq)[i];
    float4 o;
    o.x = (v.x > 0.f) ? __builtin_amdgcn_rcpf(v.x) : 0.f;
    o.y = (v.y > 0.f) ? __builtin_amdgcn_rcpf(v.y) : 0.f;
    o.z = (v.z > 0.f) ? __builtin_amdgcn_rcpf(v.z) : 0.f;
    o.w = (v.w > 0.f) ? __builtin_amdgcn_rcpf(v.w) : 0.f;
    reinterpret_cast<float4*>(cq)[i] = o;
}

// ---------------------------------------------------------------- pass 2: w_k += partial sum_q exp2(s)*invl[q]
__global__ __launch_bounds__(256) void kw_mfma_kernel(const short8* __restrict__ qbf,
                                                      const short8* __restrict__ kbf,
                                                      const float* __restrict__ cq,
                                                      float* __restrict__ wk) {
    int bh = blockIdx.x, wv = threadIdx.x >> 6, lane = threadIdx.x & 63;
    int z  = blockIdx.z;                         // q-quarter
    int kt0 = (blockIdx.y*4 + wv)*4;             // 4 k-tiles of 16
    short8 bk0[4], bk1[4];
    #pragma unroll
    for (int j = 0; j < 4; j++) {
        const short8* kp = kbf + (((size_t)(bh*128 + kt0 + j)*2) << 6) + lane;
        bk0[j] = kp[0]; bk1[j] = kp[64];
    }
    const short8* qp = qbf + ((size_t)bh << 14) + lane + (size_t)z*4096;
    const float4* cp = reinterpret_cast<const float4*>(cq + (size_t)bh*L_SEQ) + (lane >> 4) + z*128;
    const f32x4 z4 = {0.f, 0.f, 0.f, 0.f};
    float w[4][4] = {};
    for (int t = 0; t < 32; t++) {
        short8 a0 = qp[0], a1 = qp[64];
        qp += 128;
        float4 c4 = cp[0]; cp += 4;              // invl for rows q = z*512 + t*16 + (lane>>4)*4 + r
        float cr[4] = {c4.x, c4.y, c4.z, c4.w};
        #pragma unroll
        for (int j = 0; j < 4; j++) {
            f32x4 acc = __builtin_amdgcn_mfma_f32_16x16x32_bf16(a0, bk0[j], z4, 0, 0, 0);
            acc = __builtin_amdgcn_mfma_f32_16x16x32_bf16(a1, bk1[j], acc, 0, 0, 0);
            #pragma unroll
            for (int r = 0; r < 4; r++) {
                float p = __builtin_amdgcn_exp2f(acc[r]);
                w[j][r] += (acc[r] != 0.f) ? p*cr[r] : 0.f;
            }
        }
    }
    #pragma unroll
    for (int j = 0; j < 4; j++) {
        float s = (w[j][0] + w[j][1]) + (w[j][2] + w[j][3]);
        s += __shfl_xor(s, 16);
        s += __shfl_xor(s, 32);
        w[j][0] = s;
    }
    if (lane < 16) {
        #pragma unroll
        for (int j = 0; j < 4; j++)
            atomicAdd(&wk[(size_t)bh*L_SEQ + (kt0+j)*16 + lane], w[j][0]);
    }
}

// ---------------------------------------------------------------- pass 3: O = sum_k w_k * V_k (bf16 V)
__global__ __launch_bounds__(256) void pv_kernel(const short* __restrict__ vg_s,
                                                 const float* __restrict__ wk,
                                                 float* __restrict__ O) {
    __shared__ float red[256];
    int bidx = blockIdx.x;                       // 0..63
    int seg  = blockIdx.y;                       // 0..7 (256 keys each)
    int t    = threadIdx.x;
    int d    = t & 63;
    int ks   = t >> 6;                           // 0..3
    const short* vrow = vg_s + ((size_t)bidx*L_SEQ + seg*256)*DH;
    const float* wrow = wk + (size_t)bidx*L_SEQ + seg*256;
    float acc = 0.f;
    for (int k = ks; k < 256; k += 4)
        acc += wrow[k] * bf2f(vrow[k*64 + d]);
    red[t] = acc;
    __syncthreads();
    if (t < 128) red[t] += red[t + 128];
    __syncthreads();
    if (t < 64) atomicAdd(&O[bidx*64 + t], red[t] + red[t + 64]);
}

// ---------------------------------------------------------------- GN + residual + LN -> x, xn
__global__ __launch_bounds__(256) void ln_kernel(const float* __restrict__ O,
                                                 const float* __restrict__ embsum,
                                                 const int* __restrict__ lens,
                                                 const float* __restrict__ gn_w,
                                                 const float* __restrict__ gn_b,
                                                 const float* __restrict__ ln_w,
                                                 const float* __restrict__ ln_b,
                                                 float* __restrict__ xbuf,
                                                 float* __restrict__ xnbuf) {
    int b = blockIdx.x;
    int t = threadIdx.x;
    __shared__ float x[EMB];
    __shared__ float rbuf[16];
    {
        int h = t >> 5;            // 0..7
        int i32 = t & 31;
        float v0 = O[b*EMB + h*64 + i32];
        float v1 = O[b*EMB + h*64 + i32 + 32];
        float s = v0+v1, ss = v0*v0 + v1*v1;
        #pragma unroll
        for (int off = 16; off >= 1; off >>= 1) {
            s  += __shfl_xor(s,  off, 32);
            ss += __shfl_xor(ss, off, 32);
        }
        float mu  = s * (1.f/64.f);
        float var = ss * (1.f/64.f) - mu*mu;
        float rstd = rsqrtf(var + 1e-5f);
        float gw = gn_w[h], gb = gn_b[h];
        float len = (float)lens[b];
        x[h*64+i32]    = (v0-mu)*rstd*gw + gb + embsum[b*EMB + h*64+i32] / len;
        x[h*64+i32+32] = (v1-mu)*rstd*gw + gb + embsum[b*EMB + h*64+i32+32] / len;
    }
    __syncthreads();
    float xv0 = x[t], xv1 = x[t+256];
    {
        float s = xv0+xv1, ss = xv0*xv0 + xv1*xv1;
        #pragma unroll
        for (int off = 32; off >= 1; off >>= 1) {
            s  += __shfl_xor(s,  off);
            ss += __shfl_xor(ss, off);
        }
        int wid = t >> 6;
        if ((t & 63) == 0) { rbuf[wid] = s; rbuf[8+wid] = ss; }
        __syncthreads();
        float S  = rbuf[0]+rbuf[1]+rbuf[2]+rbuf[3];
        float SS = rbuf[8]+rbuf[9]+rbuf[10]+rbuf[11];
        float mu  = S * (1.f/512.f);
        float var = SS * (1.f/512.f) - mu*mu;
        float rstd = rsqrtf(var + 1e-5f);
        xnbuf[b*EMB + t]       = (xv0-mu)*rstd*ln_w[t]     + ln_b[t];
        xnbuf[b*EMB + t + 256] = (xv1-mu)*rstd*ln_w[t+256] + ln_b[t+256];
        xbuf[b*EMB + t]        = xv0;
        xbuf[b*EMB + t + 256]  = xv1;
    }
}

// ---------------------------------------------------------------- MLP layer 1: h1 = tanh(xn @ w1^T + b1)
__global__ __launch_bounds__(256) void mlp1_kernel(const float* __restrict__ xnbuf,
                                                   const float* __restrict__ w1,
                                                   const float* __restrict__ b1,
                                                   float* __restrict__ h1buf) {
    __shared__ float sxn[BS][EMB];     // 16KB
    int t = threadIdx.x;
    #pragma unroll
    for (int i = 0; i < 4; i++)
        reinterpret_cast<float4*>(&sxn[0][0])[t + 256*i] =
            reinterpret_cast<const float4*>(xnbuf)[t + 256*i];
    __syncthreads();
    int b = t & 7;
    int j = blockIdx.x*32 + (t >> 3);  // 0..1023
    const float4* wr = reinterpret_cast<const float4*>(w1 + (size_t)j*512);
    const float4* xr = reinterpret_cast<const float4*>(&sxn[b][0]);
    float a0 = 0.f, a1 = 0.f;
    #pragma unroll 8
    for (int i = 0; i < 128; i += 2) {
        float4 wv = wr[i],   xv = xr[i];
        a0 += wv.x*xv.x + wv.y*xv.y + wv.z*xv.z + wv.w*xv.w;
        float4 wv1 = wr[i+1], xv1 = xr[i+1];
        a1 += wv1.x*xv1.x + wv1.y*xv1.y + wv1.z*xv1.z + wv1.w*xv1.w;
    }
    h1buf[b*1024 + j] = tanhf(a0 + a1 + b1[j]);
}

// ---------------------------------------------------------------- MLP layer 2: out = x + h1 @ w2^T + b2
__global__ __launch_bounds__(256) void mlp2_kernel(const float* __restrict__ h1buf,
                                                   const float* __restrict__ xbuf,
                                                   const float* __restrict__ w2,
                                                   const float* __restrict__ b2,
                                                   float* __restrict__ out) {
    __shared__ float sh1[BS][2*EMB];   // 32KB
    int t = threadIdx.x;
    #pragma unroll
    for (int i = 0; i < 8; i++)
        reinterpret_cast<float4*>(&sh1[0][0])[t + 256*i] =
            reinterpret_cast<const float4*>(h1buf)[t + 256*i];
    __syncthreads();
    int b = t & 7;
    int e = blockIdx.x*32 + (t >> 3);  // 0..511
    const float4* wr = reinterpret_cast<const float4*>(w2 + (size_t)e*1024);
    const float4* hr = reinterpret_cast<const float4*>(&sh1[b][0]);
    float a0 = 0.f, a1 = 0.f;
    #pragma unroll 8
    for (int i = 0; i < 256; i += 2) {
        float4 wv = wr[i],   hv = hr[i];
        a0 += wv.x*hv.x + wv.y*hv.y + wv.z*hv.z + wv.w*hv.w;
        float4 wv1 = wr[i+1], hv1 = hr[i+1];
        a1 += wv1.x*hv1.x + wv1.y*hv1.y + wv1.z*hv1.z + wv1.w*hv1.w;
    }
    out[b*EMB + e] = xbuf[b*EMB + e] + a0 + a1 + b2[e];
}

// ---------------------------------------------------------------- launch
extern "C" void kernel_launch(void* const* d_in, const int* in_sizes, int n_in,
                              void* d_out, int out_size, void* d_ws, size_t ws_size,
                              hipStream_t stream) {
    const int*   inputs    = (const int*)d_in[0];
    const int*   lens      = (const int*)d_in[1];
    const float* emb_table = (const float*)d_in[2];
    const float* qkv_w     = (const float*)d_in[3];
    const float* qkv_b     = (const float*)d_in[4];
    const float* gn_w      = (const float*)d_in[5];
    const float* gn_b      = (const float*)d_in[6];
    const float* ln_w      = (const float*)d_in[7];
    const float* ln_b      = (const float*)d_in[8];
    const float* w1        = (const float*)d_in[9];
    const float* b1        = (const float*)d_in[10];
    const float* w2        = (const float*)d_in[11];
    const float* b2        = (const float*)d_in[12];
    float* out = (float*)d_out;

    // ---- workspace map (floats). OFFSETS IDENTICAL TO R7..R11 (proven).
    float* ws = (float*)d_ws;
    const size_t NE = (size_t)L_SEQ*BS*EMB;       // 8,388,608
    float* emb    = ws;                           // region reused by kbf/qbf only
    float* vg     = emb + NE;                     // bf16 rows (half the region used)
    float* pe_res = vg  + NE;                     // reserved
    float* afrag  = pe_res + (size_t)L_SEQ*EMB;
    short* ahi_s  = reinterpret_cast<short*>(afrag);
    float* qkrows = afrag + NE;                   // unused; reserved
    float* wfrag  = qkrows + NE;
    short8* bhi   = reinterpret_cast<short8*>(wfrag);
    short8* blo   = bhi + 98304;
    float* cqbuf  = wfrag + 786432;               // past BOTH bhi and blo
    float* wkbuf  = cqbuf + (size_t)NB*L_SEQ;     // 131072
    float* freq   = wkbuf + (size_t)NB*L_SEQ;     // 256 (reserved; freq inline)
    float* embsum = freq + 256;                   // 4096
    float* Oacc   = embsum + BS*EMB;              // 4096
    float* xbuf   = Oacc + NB*DH;                 // 4096
    float* xnbuf  = xbuf + BS*EMB;                // 4096
    float* h1buf  = xnbuf + BS*EMB;               // 8192
    // q/k frag buffers alias emb region (written by qkv epilogue)
    short8* kbf = reinterpret_cast<short8*>(emb);             // 16 MB
    short8* qbf = kbf + (size_t)NB*128*2*64;                  // 16 MB

    // one memset covers cq + wk + freq(reserved) + embsum + Oacc (contiguous)
    hipMemsetAsync(cqbuf, 0, (2*(size_t)NB*L_SEQ + 256 + 2*BS*EMB) * sizeof(float), stream);

    embed_kernel<<<dim3(BS, 16, 4), 256, 0, stream>>>(inputs, emb_table, ahi_s, embsum);
    wsplit_kernel<<<384, 256, 0, stream>>>(qkv_w, bhi, blo);
    qkv_mfma_kernel<<<1536, 256, 0, stream>>>(reinterpret_cast<const short8*>(ahi_s),
                                              bhi, blo, qkv_b,
                                              reinterpret_cast<short*>(qbf),
                                              reinterpret_cast<short*>(kbf),
                                              reinterpret_cast<short*>(vg));
    ml_mfma_kernel<<<dim3(NB, 8, 4), 256, 0, stream>>>(qbf, kbf, cqbuf);
    inv_kernel<<<128, 256, 0, stream>>>(cqbuf);
    kw_mfma_kernel<<<dim3(NB, 8, 4), 256, 0, stream>>>(qbf, kbf, cqbuf, wkbuf);
    pv_kernel<<<dim3(NB, 8), 256, 0, stream>>>(reinterpret_cast<const short*>(vg), wkbuf, Oacc);
    ln_kernel<<<BS, 256, 0, stream>>>(Oacc, embsum, lens, gn_w, gn_b, ln_w, ln_b, xbuf, xnbuf);
    mlp1_kernel<<<32, 256, 0, stream>>>(xnbuf, w1, b1, h1buf);
    mlp2_kernel<<<16, 256, 0, stream>>>(h1buf, xbuf, w2, b2, out);
}